// Round 4
// baseline (749.139 us; speedup 1.0000x reference)
//
#include <hip/hip_runtime.h>
#include <math.h>

#define G 8192
#define D 1024
#define E 64
#define CAP 160
#define SLAB (E*CAP)                      // 10240 floats per token per tensor
#define OFF_COMB ((size_t)G*SLAB)         // 83886080
#define OFF_LOSS ((size_t)2*(size_t)G*SLAB)
#define OFF_M1 (OFF_LOSS+1)
#define OFF_M2 (OFF_M1+64)

typedef float vf4 __attribute__((ext_vector_type(4)));   // native vector for nt stores

// workspace element offsets (4B elements)
#define W_E1 0
#define W_E2 8192
#define W_R1 16384
#define W_R2 24576
#define W_G1 32768
#define W_G2 40960
#define W_H1 49152
#define W_H2 (49152+2048)
#define W_B1 (49152+4096)
#define W_B2 (49152+6144)
#define W_C1K (49152+8192)
#define W_SP  (49152+8192+64)             // 512 blocks * 64 floats
#define W_REC (W_SP+512*64)               // 8192 tokens * 4 floats (tgt1,tgt2,g1,g2)

// ---------------- Kernel 1: GEMM + softmax + top2 (fp32) ----------------
// grid 512 blocks x 256 thr. Wave = 64 lanes (lane <-> expert), 4 tokens/wave.
// x staged in LDS (read back as same-address float4 broadcast), w column in regs.
__global__ __launch_bounds__(256) void k_gating(const float* __restrict__ x,
                                                const float* __restrict__ w,
                                                int* __restrict__ wsi,
                                                float* __restrict__ wsf) {
  const int lane = threadIdx.x & 63;
  const int wid  = threadIdx.x >> 6;
  const int nblk = blockIdx.x * 16;      // 16 tokens per block
  const int n0   = nblk + wid * 4;       // 4 tokens per wave

  __shared__ float xs[16][64];           // 4 KB chunk of x
  float acc[4] = {0.f, 0.f, 0.f, 0.f};

  const int stok = threadIdx.x >> 4;           // 0..15 (staging token)
  const int sk   = (threadIdx.x & 15) * 4;     // 0..60 (staging k offset)
  const float* xsrc = x + (size_t)(nblk + stok) * D + sk;

  for (int kc = 0; kc < D; kc += 64) {
    *(float4*)&xs[stok][sk] = *(const float4*)(xsrc + kc);
    float wr[64];
#pragma unroll
    for (int j = 0; j < 64; ++j) wr[j] = w[(size_t)(kc + j) * E + lane];
    __syncthreads();
#pragma unroll
    for (int t = 0; t < 4; ++t) {
      const int tok = wid * 4 + t;
      float a = acc[t];
#pragma unroll
      for (int j4 = 0; j4 < 16; ++j4) {
        const float4 xv = *(const float4*)&xs[tok][j4 * 4];   // broadcast b128
        a = fmaf(xv.x, wr[j4*4+0], a);
        a = fmaf(xv.y, wr[j4*4+1], a);
        a = fmaf(xv.z, wr[j4*4+2], a);
        a = fmaf(xv.w, wr[j4*4+3], a);
      }
      acc[t] = a;
    }
    __syncthreads();
  }

  __shared__ float sp[256];
  float ps = 0.f;   // per-lane (expert) softmax-prob partial sum over this wave's tokens

  for (int t = 0; t < 4; ++t) {
    float v = acc[t];
    // top-1 (stable: lowest index on ties, matches jax.lax.top_k)
    float m = v; int mi = lane;
    for (int off = 32; off > 0; off >>= 1) {
      float ov = __shfl_xor(m, off, 64);
      int   oi = __shfl_xor(mi, off, 64);
      if (ov > m || (ov == m && oi < mi)) { m = ov; mi = oi; }
    }
    // top-2
    float v2 = (lane == mi) ? -__builtin_inff() : v;
    float m2 = v2; int mi2 = lane;
    for (int off = 32; off > 0; off >>= 1) {
      float ov = __shfl_xor(m2, off, 64);
      int   oi = __shfl_xor(mi2, off, 64);
      if (ov > m2 || (ov == m2 && oi < mi2)) { m2 = ov; mi2 = oi; }
    }
    float ex = expf(v - m);
    float den = ex;
    for (int off = 32; off > 0; off >>= 1) den += __shfl_xor(den, off, 64);
    ps += ex / den;

    float g1 = 1.0f / den;            // exp(0)/den
    float g2 = expf(m2 - m) / den;
    float s  = g1 + g2 + 1e-9f;
    float ga = g1 / s, gb = g2 / s;
    if (lane == 0) {
      int n = n0 + t;
      wsi[W_E1 + n] = mi;
      wsi[W_E2 + n] = mi2;
      wsf[W_G1 + n] = ga;
      wsf[W_G2 + n] = gb;
    }
  }
  sp[threadIdx.x] = ps;
  __syncthreads();
  if (threadIdx.x < 64) {
    wsf[W_SP + blockIdx.x * 64 + threadIdx.x] =
      sp[threadIdx.x] + sp[64 + threadIdx.x] + sp[128 + threadIdx.x] + sp[192 + threadIdx.x];
  }
}

// ---------------- Kernel 2: per-chunk ranks + histograms ----------------
// grid 32 blocks x 256 thr; chunk = 256 tokens.
__global__ __launch_bounds__(256) void k_rank(int* __restrict__ wsi) {
  __shared__ int hw1[4][64], hw2[4][64];
  const int t = threadIdx.x, b = blockIdx.x;
  const int lane = t & 63, w = t >> 6;
  if (t < 64) { for (int i = 0; i < 4; ++i) { hw1[i][t] = 0; hw2[i][t] = 0; } }
  __syncthreads();
  const int n = b * 256 + t;
  const int a  = wsi[W_E1 + n];
  const int e2 = wsi[W_E2 + n];
  int c1 = 0, c2 = 0;
  for (int j = 0; j < 64; ++j) {
    int ja = __shfl(a, j, 64);
    int jb = __shfl(e2, j, 64);
    if (j < lane) { c1 += (ja == a); c2 += (jb == e2); }
  }
  atomicAdd(&hw1[w][a], 1);
  atomicAdd(&hw2[w][e2], 1);
  __syncthreads();
  for (int ww = 0; ww < w; ++ww) { c1 += hw1[ww][a]; c2 += hw2[ww][e2]; }
  wsi[W_R1 + n] = c1;
  wsi[W_R2 + n] = c2;
  if (t < 64)
    wsi[W_H1 + b*64 + t] = hw1[0][t] + hw1[1][t] + hw1[2][t] + hw1[3][t];
  else if (t < 128) {
    int e = t - 64;
    wsi[W_H2 + b*64 + e] = hw2[0][e] + hw2[1][e] + hw2[2][e] + hw2[3][e];
  }
}

// ---------------- Kernel 3: cross-chunk prefix + counts + loss ----------------
// single block, 64 threads (thread = expert)
__global__ __launch_bounds__(64) void k_scan(int* __restrict__ wsi,
                                             const float* __restrict__ wsf,
                                             float* __restrict__ out) {
  const int e = threadIdx.x;
  int run1 = 0, run2 = 0;
  for (int c = 0; c < 32; ++c) {
    wsi[W_B1 + c*64 + e] = run1; run1 += wsi[W_H1 + c*64 + e];
    wsi[W_B2 + c*64 + e] = run2; run2 += wsi[W_H2 + c*64 + e];
  }
  int c1k = min(run1, CAP);
  wsi[W_C1K + e] = c1k;
  int m2c = min(run2, max(0, CAP - c1k));
  out[OFF_M1 + e] = (float)c1k;
  out[OFF_M2 + e] = (float)m2c;
  // loss = mean_e( (sumprob/8192) * (count1/8192) ) * 64^2
  float s = 0.f;
  for (int b = 0; b < 512; ++b) s += wsf[W_SP + b*64 + e];
  float term = (s * (1.0f/8192.f)) * ((float)run1 * (1.0f/8192.f));
  for (int off = 32; off > 0; off >>= 1) term += __shfl_xor(term, off, 64);
  if (e == 0) out[OFF_LOSS] = (term * (1.0f/64.f)) * 4096.0f;
}

// ---------------- Kernel 3b: per-token record {tgt1, tgt2, g1, g2} ----------------
// 32 blocks x 256 thr
__global__ __launch_bounds__(256) void k_prep(const int* __restrict__ wsi,
                                              const float* __restrict__ wsf,
                                              float* __restrict__ wso) {
  const int n = blockIdx.x * 256 + threadIdx.x;
  const int e1 = wsi[W_E1 + n];
  const int e2 = wsi[W_E2 + n];
  const int c = n >> 8;
  const int p1 = wsi[W_B1 + c*64 + e1] + wsi[W_R1 + n];
  const int p2 = wsi[W_B2 + c*64 + e2] + wsi[W_R2 + n] + wsi[W_C1K + e2];
  const float g1 = wsf[W_G1 + n];
  const float g2 = wsf[W_G2 + n];
  // combine entry exists iff position < CAP and gate nonzero
  // (dispatch = (combine != 0), so g2 underflow-to-0 must kill dispatch too)
  const int tgt1 = (p1 < CAP && g1 != 0.0f) ? (e1 * CAP + p1) : -100;
  const int tgt2 = (p2 < CAP && g2 != 0.0f) ? (e2 * CAP + p2) : -100;
  vf4 rec;
  rec.x = __int_as_float(tgt1);
  rec.y = __int_as_float(tgt2);
  rec.z = g1;
  rec.w = g2;
  *(vf4*)&wso[W_REC + 4*n] = rec;
}

// ---------------- Kernel 4: fill dispatch + combine ----------------
// one block per token; zero-fill 2 x 10240 floats via nontemporal stores,
// inject <=2 nonzeros inline. One 16B record load per block.
__global__ __launch_bounds__(256) void k_fill(const float* __restrict__ wsf,
                                              float* __restrict__ out) {
  const int n = blockIdx.x;
  const int t = threadIdx.x;
  const vf4 rec = *(const vf4*)&wsf[W_REC + 4*n];
  const int tgt1 = __float_as_int(rec.x);
  const int tgt2 = __float_as_int(rec.y);
  const float g1 = rec.z, g2 = rec.w;

  vf4* __restrict__ dp = (vf4*)out + (size_t)n * (SLAB/4);
  vf4* __restrict__ cp = (vf4*)(out + OFF_COMB) + (size_t)n * (SLAB/4);
#pragma unroll
  for (int i = 0; i < 5; ++i) {
    const int idx0 = i * 512 + t;          // two float4s per tensor per iter
    const int idx1 = idx0 + 256;
#pragma unroll
    for (int u = 0; u < 2; ++u) {
      const int idx = u ? idx1 : idx0;
      const int f = idx * 4;
      vf4 dv, cv;
      dv.x = (f     == tgt1 || f     == tgt2) ? 1.f : 0.f;
      dv.y = (f + 1 == tgt1 || f + 1 == tgt2) ? 1.f : 0.f;
      dv.z = (f + 2 == tgt1 || f + 2 == tgt2) ? 1.f : 0.f;
      dv.w = (f + 3 == tgt1 || f + 3 == tgt2) ? 1.f : 0.f;
      cv.x = (f     == tgt1) ? g1 : ((f     == tgt2) ? g2 : 0.f);
      cv.y = (f + 1 == tgt1) ? g1 : ((f + 1 == tgt2) ? g2 : 0.f);
      cv.z = (f + 2 == tgt1) ? g1 : ((f + 2 == tgt2) ? g2 : 0.f);
      cv.w = (f + 3 == tgt1) ? g1 : ((f + 3 == tgt2) ? g2 : 0.f);
      __builtin_nontemporal_store(dv, &dp[idx]);
      __builtin_nontemporal_store(cv, &cp[idx]);
    }
  }
}

extern "C" void kernel_launch(void* const* d_in, const int* in_sizes, int n_in,
                              void* d_out, int out_size, void* d_ws, size_t ws_size,
                              hipStream_t stream) {
  const float* x = (const float*)d_in[0];
  const float* w = (const float*)d_in[1];
  float* out = (float*)d_out;
  int*   wsi = (int*)d_ws;
  float* wsf = (float*)d_ws;

  k_gating<<<512, 256, 0, stream>>>(x, w, wsi, wsf);
  k_rank  <<<32, 256, 0, stream>>>(wsi);
  k_scan  <<<1, 64, 0, stream>>>(wsi, wsf, out);
  k_prep  <<<32, 256, 0, stream>>>(wsi, wsf, wsf);
  k_fill  <<<8192, 256, 0, stream>>>(wsf, out);
}

// Round 5
// 704.607 us; speedup vs baseline: 1.0632x; 1.0632x over previous
//
#include <hip/hip_runtime.h>
#include <math.h>

#define G 8192
#define D 1024
#define E 64
#define CAP 160
#define SLAB (E*CAP)                      // 10240 floats per token per tensor
#define OFF_COMB ((size_t)G*SLAB)         // 83886080
#define OFF_LOSS ((size_t)2*(size_t)G*SLAB)
#define OFF_M1 (OFF_LOSS+1)
#define OFF_M2 (OFF_M1+64)

typedef float vf4 __attribute__((ext_vector_type(4)));   // native vector for nt stores

// workspace element offsets (4B elements)
#define W_E1 0
#define W_E2 8192
#define W_R1 16384
#define W_R2 24576
#define W_G1 32768
#define W_G2 40960
#define W_H1 49152
#define W_H2 (49152+2048)
#define W_B1 (49152+4096)
#define W_B2 (49152+6144)
#define W_C1K (49152+8192)
#define W_SP  (49152+8192+64)             // 512 gating blocks * 64 floats

// ---------------- Kernel 1 (fused): gating GEMM+softmax+top2  ||  zero-fill ----------------
// grid 8704 blocks x 256 thr.
//   blocks [0,512):   gating — 16 tokens/block, wave = 64 lanes (lane<->expert), 4 tokens/wave
//   blocks [512,8704): pure nontemporal zero-fill of one token's dispatch+combine slabs (80 KB)
// Zero-fill (107 us of HBM writes) has no dependency on gating (~50 us of VALU/LDS);
// they co-schedule on different pipes -> time ~ max, not sum (m114).
__global__ __launch_bounds__(256) void k_gate_zero(const float* __restrict__ x,
                                                   const float* __restrict__ w,
                                                   int* __restrict__ wsi,
                                                   float* __restrict__ wsf,
                                                   float* __restrict__ out) {
  __shared__ float xs[16][64];           // gating path only (allocated for all blocks; 5 KB total)
  __shared__ float sp[256];

  if (blockIdx.x >= 512) {
    // ---- zero path ----
    const int n = blockIdx.x - 512;
    const int t = threadIdx.x;
    vf4 z = {0.f, 0.f, 0.f, 0.f};
    vf4* __restrict__ dp = (vf4*)out + (size_t)n * (SLAB/4);
    vf4* __restrict__ cp = (vf4*)(out + OFF_COMB) + (size_t)n * (SLAB/4);
#pragma unroll
    for (int i = 0; i < 10; ++i) {
      const int idx = i * 256 + t;
      __builtin_nontemporal_store(z, &dp[idx]);
      __builtin_nontemporal_store(z, &cp[idx]);
    }
    return;
  }

  // ---- gating path ----
  const int lane = threadIdx.x & 63;
  const int wid  = threadIdx.x >> 6;
  const int nblk = blockIdx.x * 16;      // 16 tokens per block
  const int n0   = nblk + wid * 4;       // 4 tokens per wave

  float acc[4] = {0.f, 0.f, 0.f, 0.f};

  const int stok = threadIdx.x >> 4;           // 0..15 (staging token)
  const int sk   = (threadIdx.x & 15) * 4;     // 0..60 (staging k offset)
  const float* xsrc = x + (size_t)(nblk + stok) * D + sk;

  for (int kc = 0; kc < D; kc += 64) {
    *(float4*)&xs[stok][sk] = *(const float4*)(xsrc + kc);
    float wr[64];
#pragma unroll
    for (int j = 0; j < 64; ++j) wr[j] = w[(size_t)(kc + j) * E + lane];
    __syncthreads();
#pragma unroll
    for (int t = 0; t < 4; ++t) {
      const int tok = wid * 4 + t;
      float a = acc[t];
#pragma unroll
      for (int j4 = 0; j4 < 16; ++j4) {
        const float4 xv = *(const float4*)&xs[tok][j4 * 4];   // broadcast b128
        a = fmaf(xv.x, wr[j4*4+0], a);
        a = fmaf(xv.y, wr[j4*4+1], a);
        a = fmaf(xv.z, wr[j4*4+2], a);
        a = fmaf(xv.w, wr[j4*4+3], a);
      }
      acc[t] = a;
    }
    __syncthreads();
  }

  float ps = 0.f;   // per-lane (expert) softmax-prob partial sum over this wave's tokens

  for (int t = 0; t < 4; ++t) {
    float v = acc[t];
    // top-1 (stable: lowest index on ties, matches jax.lax.top_k)
    float m = v; int mi = lane;
    for (int off = 32; off > 0; off >>= 1) {
      float ov = __shfl_xor(m, off, 64);
      int   oi = __shfl_xor(mi, off, 64);
      if (ov > m || (ov == m && oi < mi)) { m = ov; mi = oi; }
    }
    // top-2
    float v2 = (lane == mi) ? -__builtin_inff() : v;
    float m2 = v2; int mi2 = lane;
    for (int off = 32; off > 0; off >>= 1) {
      float ov = __shfl_xor(m2, off, 64);
      int   oi = __shfl_xor(mi2, off, 64);
      if (ov > m2 || (ov == m2 && oi < mi2)) { m2 = ov; mi2 = oi; }
    }
    float ex = expf(v - m);
    float den = ex;
    for (int off = 32; off > 0; off >>= 1) den += __shfl_xor(den, off, 64);
    ps += ex / den;

    float g1 = 1.0f / den;            // exp(0)/den
    float g2 = expf(m2 - m) / den;
    float s  = g1 + g2 + 1e-9f;
    float ga = g1 / s, gb = g2 / s;
    if (lane == 0) {
      int n = n0 + t;
      wsi[W_E1 + n] = mi;
      wsi[W_E2 + n] = mi2;
      wsf[W_G1 + n] = ga;
      wsf[W_G2 + n] = gb;
    }
  }
  sp[threadIdx.x] = ps;
  __syncthreads();
  if (threadIdx.x < 64) {
    wsf[W_SP + blockIdx.x * 64 + threadIdx.x] =
      sp[threadIdx.x] + sp[64 + threadIdx.x] + sp[128 + threadIdx.x] + sp[192 + threadIdx.x];
  }
}

// ---------------- Kernel 2: per-chunk ranks + histograms ----------------
// grid 32 blocks x 256 thr; chunk = 256 tokens.
__global__ __launch_bounds__(256) void k_rank(int* __restrict__ wsi) {
  __shared__ int hw1[4][64], hw2[4][64];
  const int t = threadIdx.x, b = blockIdx.x;
  const int lane = t & 63, w = t >> 6;
  if (t < 64) { for (int i = 0; i < 4; ++i) { hw1[i][t] = 0; hw2[i][t] = 0; } }
  __syncthreads();
  const int n = b * 256 + t;
  const int a  = wsi[W_E1 + n];
  const int e2 = wsi[W_E2 + n];
  int c1 = 0, c2 = 0;
  for (int j = 0; j < 64; ++j) {
    int ja = __shfl(a, j, 64);
    int jb = __shfl(e2, j, 64);
    if (j < lane) { c1 += (ja == a); c2 += (jb == e2); }
  }
  atomicAdd(&hw1[w][a], 1);
  atomicAdd(&hw2[w][e2], 1);
  __syncthreads();
  for (int ww = 0; ww < w; ++ww) { c1 += hw1[ww][a]; c2 += hw2[ww][e2]; }
  wsi[W_R1 + n] = c1;
  wsi[W_R2 + n] = c2;
  if (t < 64)
    wsi[W_H1 + b*64 + t] = hw1[0][t] + hw1[1][t] + hw1[2][t] + hw1[3][t];
  else if (t < 128) {
    int e = t - 64;
    wsi[W_H2 + b*64 + e] = hw2[0][e] + hw2[1][e] + hw2[2][e] + hw2[3][e];
  }
}

// ---------------- Kernel 3: cross-chunk prefix + counts + loss ----------------
// single block, 64 threads (thread = expert)
__global__ __launch_bounds__(64) void k_scan(int* __restrict__ wsi,
                                             const float* __restrict__ wsf,
                                             float* __restrict__ out) {
  const int e = threadIdx.x;
  int run1 = 0, run2 = 0;
  for (int c = 0; c < 32; ++c) {
    wsi[W_B1 + c*64 + e] = run1; run1 += wsi[W_H1 + c*64 + e];
    wsi[W_B2 + c*64 + e] = run2; run2 += wsi[W_H2 + c*64 + e];
  }
  int c1k = min(run1, CAP);
  wsi[W_C1K + e] = c1k;
  int m2c = min(run2, max(0, CAP - c1k));
  out[OFF_M1 + e] = (float)c1k;
  out[OFF_M2 + e] = (float)m2c;
  // loss = mean_e( (sumprob/8192) * (count1/8192) ) * 64^2
  float s = 0.f;
  for (int b = 0; b < 512; ++b) s += wsf[W_SP + b*64 + e];
  float term = (s * (1.0f/8192.f)) * ((float)run1 * (1.0f/8192.f));
  for (int off = 32; off > 0; off >>= 1) term += __shfl_xor(term, off, 64);
  if (e == 0) out[OFF_LOSS] = (term * (1.0f/64.f)) * 4096.0f;
}

// ---------------- Kernel 4: scatter nonzeros into the pre-zeroed tensors ----------------
// 32 blocks x 256 thr, one thread per token: <=4 scattered 4B stores.
__global__ __launch_bounds__(256) void k_scatter(const int* __restrict__ wsi,
                                                 const float* __restrict__ wsf,
                                                 float* __restrict__ out) {
  const int n = blockIdx.x * 256 + threadIdx.x;
  const int e1 = wsi[W_E1 + n];
  const int e2 = wsi[W_E2 + n];
  const int c = n >> 8;
  const int p1 = wsi[W_B1 + c*64 + e1] + wsi[W_R1 + n];
  const int p2 = wsi[W_B2 + c*64 + e2] + wsi[W_R2 + n] + wsi[W_C1K + e2];
  const float g1 = wsf[W_G1 + n];
  const float g2 = wsf[W_G2 + n];
  const size_t base = (size_t)n * SLAB;
  // combine entry exists iff position < CAP and gate nonzero
  // (dispatch = (combine != 0), so g2 underflow-to-0 must kill dispatch too)
  if (p1 < CAP && g1 != 0.0f) {
    out[base + e1 * CAP + p1] = 1.0f;
    out[OFF_COMB + base + e1 * CAP + p1] = g1;
  }
  if (p2 < CAP && g2 != 0.0f) {
    out[base + e2 * CAP + p2] = 1.0f;
    out[OFF_COMB + base + e2 * CAP + p2] = g2;
  }
}

extern "C" void kernel_launch(void* const* d_in, const int* in_sizes, int n_in,
                              void* d_out, int out_size, void* d_ws, size_t ws_size,
                              hipStream_t stream) {
  const float* x = (const float*)d_in[0];
  const float* w = (const float*)d_in[1];
  float* out = (float*)d_out;
  int*   wsi = (int*)d_ws;
  float* wsf = (float*)d_ws;

  k_gate_zero<<<8704, 256, 0, stream>>>(x, w, wsi, wsf, out);
  k_rank     <<<32, 256, 0, stream>>>(wsi);
  k_scan     <<<1, 64, 0, stream>>>(wsi, wsf, out);
  k_scatter  <<<32, 256, 0, stream>>>(wsi, wsf, out);
}

// Round 6
// 698.938 us; speedup vs baseline: 1.0718x; 1.0081x over previous
//
#include <hip/hip_runtime.h>
#include <math.h>

#define G 8192
#define D 1024
#define E 64
#define CAP 160
#define SLAB (E*CAP)                      // 10240 floats per token per tensor
#define OFF_COMB ((size_t)G*SLAB)         // 83886080
#define OFF_LOSS ((size_t)2*(size_t)G*SLAB)
#define OFF_M1 (OFF_LOSS+1)
#define OFF_M2 (OFF_M1+64)

typedef float vf4 __attribute__((ext_vector_type(4)));   // native vector for nt stores

// workspace element offsets (4B elements)
#define W_E1 0
#define W_E2 8192
#define W_G1 32768
#define W_G2 40960
#define W_SP  (49152+8192+64)             // 512 gating blocks * 64 floats

// ---------------- Kernel 1 (fused): gating GEMM+softmax+top2  ||  zero-fill ----------------
// grid 8704 blocks x 256 thr.
//   blocks [0,512):   gating — 16 tokens/block, wave = 64 lanes (lane<->expert), 4 tokens/wave
//   blocks [512,8704): pure nontemporal zero-fill of one token's dispatch+combine slabs (80 KB)
// Zero-fill (~107 us of HBM writes) has no dependency on gating (~VALU/LDS/L2-bound);
// they co-schedule on different pipes -> time ~ max, not sum (m114).
__global__ __launch_bounds__(256) void k_gate_zero(const float* __restrict__ x,
                                                   const float* __restrict__ w,
                                                   int* __restrict__ wsi,
                                                   float* __restrict__ wsf,
                                                   float* __restrict__ out) {
  __shared__ float xs[16][64];
  __shared__ float sp[256];

  if (blockIdx.x >= 512) {
    // ---- zero path ----
    const int n = blockIdx.x - 512;
    const int t = threadIdx.x;
    vf4 z = {0.f, 0.f, 0.f, 0.f};
    vf4* __restrict__ dp = (vf4*)out + (size_t)n * (SLAB/4);
    vf4* __restrict__ cp = (vf4*)(out + OFF_COMB) + (size_t)n * (SLAB/4);
#pragma unroll
    for (int i = 0; i < 10; ++i) {
      const int idx = i * 256 + t;
      __builtin_nontemporal_store(z, &dp[idx]);
      __builtin_nontemporal_store(z, &cp[idx]);
    }
    return;
  }

  // ---- gating path ----
  const int lane = threadIdx.x & 63;
  const int wid  = threadIdx.x >> 6;
  const int nblk = blockIdx.x * 16;      // 16 tokens per block
  const int n0   = nblk + wid * 4;       // 4 tokens per wave

  float acc[4] = {0.f, 0.f, 0.f, 0.f};

  const int stok = threadIdx.x >> 4;           // 0..15 (staging token)
  const int sk   = (threadIdx.x & 15) * 4;     // 0..60 (staging k offset)
  const float* xsrc = x + (size_t)(nblk + stok) * D + sk;

  for (int kc = 0; kc < D; kc += 64) {
    *(float4*)&xs[stok][sk] = *(const float4*)(xsrc + kc);
    float wr[64];
#pragma unroll
    for (int j = 0; j < 64; ++j) wr[j] = w[(size_t)(kc + j) * E + lane];
    __syncthreads();
#pragma unroll
    for (int t = 0; t < 4; ++t) {
      const int tok = wid * 4 + t;
      float a = acc[t];
#pragma unroll
      for (int j4 = 0; j4 < 16; ++j4) {
        const float4 xv = *(const float4*)&xs[tok][j4 * 4];   // broadcast b128
        a = fmaf(xv.x, wr[j4*4+0], a);
        a = fmaf(xv.y, wr[j4*4+1], a);
        a = fmaf(xv.z, wr[j4*4+2], a);
        a = fmaf(xv.w, wr[j4*4+3], a);
      }
      acc[t] = a;
    }
    __syncthreads();
  }

  float ps = 0.f;   // per-lane (expert) softmax-prob partial sum over this wave's tokens

  for (int t = 0; t < 4; ++t) {
    float v = acc[t];
    // top-1 (stable: lowest index on ties, matches jax.lax.top_k)
    float m = v; int mi = lane;
    for (int off = 32; off > 0; off >>= 1) {
      float ov = __shfl_xor(m, off, 64);
      int   oi = __shfl_xor(mi, off, 64);
      if (ov > m || (ov == m && oi < mi)) { m = ov; mi = oi; }
    }
    // top-2
    float v2 = (lane == mi) ? -__builtin_inff() : v;
    float m2 = v2; int mi2 = lane;
    for (int off = 32; off > 0; off >>= 1) {
      float ov = __shfl_xor(m2, off, 64);
      int   oi = __shfl_xor(mi2, off, 64);
      if (ov > m2 || (ov == m2 && oi < mi2)) { m2 = ov; mi2 = oi; }
    }
    float ex = expf(v - m);
    float den = ex;
    for (int off = 32; off > 0; off >>= 1) den += __shfl_xor(den, off, 64);
    ps += ex / den;

    float g1 = 1.0f / den;            // exp(0)/den
    float g2 = expf(m2 - m) / den;
    float s  = g1 + g2 + 1e-9f;
    float ga = g1 / s, gb = g2 / s;
    if (lane == 0) {
      int n = n0 + t;
      wsi[W_E1 + n] = mi;
      wsi[W_E2 + n] = mi2;
      wsf[W_G1 + n] = ga;
      wsf[W_G2 + n] = gb;
    }
  }
  sp[threadIdx.x] = ps;
  __syncthreads();
  if (threadIdx.x < 64) {
    wsf[W_SP + blockIdx.x * 64 + threadIdx.x] =
      sp[threadIdx.x] + sp[64 + threadIdx.x] + sp[128 + threadIdx.x] + sp[192 + threadIdx.x];
  }
}

// ---------------- Kernel 2 (fused epilogue): rank + scan + scatter + loss/counts ----------------
// 32 blocks x 256 thr; block b owns chunk b (tokens b*256..b*256+255).
// Every block REDUNDANTLY builds all 32 chunk histograms in LDS (no cross-block
// communication -> no XCD coherence hazard), scans them for its own bases + c1k,
// ranks its own chunk via wave shuffles, scatters <=4 nonzeros per token.
// Block 0 additionally writes loss and mask counts.
__global__ __launch_bounds__(256) void k_epi(const int* __restrict__ wsi,
                                             const float* __restrict__ wsf,
                                             float* __restrict__ out) {
  __shared__ int h1[32][64], h2[32][64];      // 16 KB: chunk x expert histograms
  __shared__ int hw1[4][64], hw2[4][64];      // per-wave own-chunk histograms
  __shared__ int base1_s[64], base2_s[64], c1k_s[64], run1_s[64], run2_s[64];
  __shared__ float spf[256];

  const int b = blockIdx.x, t = threadIdx.x;
  const int lane = t & 63, w = t >> 6;

  for (int i = t; i < 32 * 64; i += 256) { ((int*)h1)[i] = 0; ((int*)h2)[i] = 0; }
  if (t < 64) { for (int i = 0; i < 4; ++i) { hw1[i][t] = 0; hw2[i][t] = 0; } }
  __syncthreads();

  // all-chunk histograms (redundant per block); capture own token's experts on the way
  int my_e1 = 0, my_e2 = 0;
  for (int cc = 0; cc < 32; ++cc) {
    const int n = cc * 256 + t;
    const int a  = wsi[W_E1 + n];
    const int bb = wsi[W_E2 + n];
    if (cc == b) { my_e1 = a; my_e2 = bb; }
    atomicAdd(&h1[cc][a], 1);
    atomicAdd(&h2[cc][bb], 1);
  }
  __syncthreads();

  // per-expert totals + exclusive base at own chunk (threads 0..127)
  if (t < 64) {
    int r1 = 0, b1 = 0;
    for (int cc = 0; cc < 32; ++cc) { if (cc == b) b1 = r1; r1 += h1[cc][t]; }
    base1_s[t] = b1; run1_s[t] = r1; c1k_s[t] = min(r1, CAP);
  } else if (t < 128) {
    const int e = t - 64;
    int r2 = 0, b2 = 0;
    for (int cc = 0; cc < 32; ++cc) { if (cc == b) b2 = r2; r2 += h2[cc][e]; }
    base2_s[e] = b2; run2_s[e] = r2;
  }

  // intra-chunk ranks for own chunk (wave shuffles + per-wave histograms)
  int c1 = 0, c2 = 0;
  for (int j = 0; j < 64; ++j) {
    int ja = __shfl(my_e1, j, 64);
    int jb = __shfl(my_e2, j, 64);
    if (j < lane) { c1 += (ja == my_e1); c2 += (jb == my_e2); }
  }
  atomicAdd(&hw1[w][my_e1], 1);
  atomicAdd(&hw2[w][my_e2], 1);
  __syncthreads();
  for (int ww = 0; ww < w; ++ww) { c1 += hw1[ww][my_e1]; c2 += hw2[ww][my_e2]; }

  // scatter
  const int n = b * 256 + t;
  const int p1 = base1_s[my_e1] + c1;
  const int p2 = base2_s[my_e2] + c2 + c1k_s[my_e2];
  const float g1 = wsf[W_G1 + n];
  const float g2 = wsf[W_G2 + n];
  const size_t base = (size_t)n * SLAB;
  // combine entry exists iff position < CAP and gate nonzero
  // (dispatch = (combine != 0), so g2 underflow-to-0 must kill dispatch too)
  if (p1 < CAP && g1 != 0.0f) {
    out[base + my_e1 * CAP + p1] = 1.0f;
    out[OFF_COMB + base + my_e1 * CAP + p1] = g1;
  }
  if (p2 < CAP && g2 != 0.0f) {
    out[base + my_e2 * CAP + p2] = 1.0f;
    out[OFF_COMB + base + my_e2 * CAP + p2] = g2;
  }

  if (b != 0) return;

  // counts
  if (t < 64) {
    out[OFF_M1 + t] = (float)c1k_s[t];
    out[OFF_M2 + t] = (float)min(run2_s[t], max(0, CAP - c1k_s[t]));
  }

  // loss = mean_e( (sumprob_e/8192) * (run1_e/8192) ) * 64^2
  {
    const int e = t & 63, q = t >> 6;
    float s = 0.f;
    for (int i = 0; i < 128; ++i)
      s += wsf[W_SP + (size_t)(q * 128 + i) * 64 + e];
    spf[t] = s;
  }
  __syncthreads();
  if (t < 64) {
    float s = spf[t] + spf[64 + t] + spf[128 + t] + spf[192 + t];
    float term = (s * (1.0f/8192.f)) * ((float)run1_s[t] * (1.0f/8192.f));
    for (int off = 32; off > 0; off >>= 1) term += __shfl_xor(term, off, 64);
    if (t == 0) out[OFF_LOSS] = (term * (1.0f/64.f)) * 4096.0f;
  }
}

extern "C" void kernel_launch(void* const* d_in, const int* in_sizes, int n_in,
                              void* d_out, int out_size, void* d_ws, size_t ws_size,
                              hipStream_t stream) {
  const float* x = (const float*)d_in[0];
  const float* w = (const float*)d_in[1];
  float* out = (float*)d_out;
  int*   wsi = (int*)d_ws;
  float* wsf = (float*)d_ws;

  k_gate_zero<<<8704, 256, 0, stream>>>(x, w, wsi, wsf, out);
  k_epi      <<<32, 256, 0, stream>>>(wsi, wsf, out);
}